// Round 5
// baseline (171.596 us; speedup 1.0000x reference)
//
#include <hip/hip_runtime.h>

#define N_NODES 100000
#define N_EDGES 1600000
#define IN_DIM  128
#define HID_DIM 128
#define OUT_DIM 256

#define ECAP   192   // cap on edges into node 0 (expected ~16, Poisson; 44-sigma margin)
#define SCAP   193   // S identifiers: <= ECAP+1
#define ELCAP  4096  // cap on edges into S (expected ~290)
#define BINCAP 128   // per-S-node edge bin (expected ~16/node)

// ctrl: [0]=cnt edges into node0, [1]=elist count, [13..15]=arrival counters K4/K2/K1

#define AG __HIP_MEMORY_SCOPE_AGENT
__device__ __forceinline__ int   aload_i (const int* p)          { return __hip_atomic_load(p, __ATOMIC_RELAXED, AG); }
__device__ __forceinline__ void  astore_i(int* p, int v)         { __hip_atomic_store(p, v, __ATOMIC_RELAXED, AG); }
__device__ __forceinline__ float aload_f (const float* p)        { return __hip_atomic_load(p, __ATOMIC_RELAXED, AG); }
__device__ __forceinline__ void  astore_f(float* p, float v)     { __hip_atomic_store(p, v, __ATOMIC_RELAXED, AG); }

// ---------------- K0: zero/seed all control + small arrays ----------------
__global__ void k0_init(int* __restrict__ flag, int* __restrict__ flag2,
                        int* __restrict__ S_node, int* __restrict__ degS,
                        int* __restrict__ degT, int* __restrict__ ctrl) {
    int i = blockIdx.x * blockDim.x + threadIdx.x;
    int stride = gridDim.x * blockDim.x;
    int4* f1 = (int4*)flag;
    int4* f2 = (int4*)flag2;
    const int n4 = N_NODES / 4;
    int4 m1 = make_int4(-1, -1, -1, -1);
    for (int j = i; j < n4; j += stride) { f1[j] = m1; f2[j] = m1; }
    for (int j = i; j < SCAP; j += stride) { S_node[j] = -1; degS[j] = 0; }
    for (int j = i; j < ELCAP; j += stride) degT[j] = 0;
    if (i < 16) ctrl[i] = 0;
}

// ---------------- K1: scan dst for dst==0; last block builds S via CAS-claim ----------------
__global__ void k1_pass1(const int4* __restrict__ dst4, const int* __restrict__ src,
                         int* __restrict__ ctrl, int* __restrict__ e0src,
                         int* __restrict__ flag, int* __restrict__ S_node) {
    int i = blockIdx.x * blockDim.x + threadIdx.x;
    int stride = gridDim.x * blockDim.x;
    const int n4 = N_EDGES / 4;
    for (int q = i; q < n4; q += stride) {
        int4 d = dst4[q];
        if (d.x == 0) { int p = atomicAdd(&ctrl[0], 1); if (p < ECAP) astore_i(&e0src[p], src[4*q+0]); }
        if (d.y == 0) { int p = atomicAdd(&ctrl[0], 1); if (p < ECAP) astore_i(&e0src[p], src[4*q+1]); }
        if (d.z == 0) { int p = atomicAdd(&ctrl[0], 1); if (p < ECAP) astore_i(&e0src[p], src[4*q+2]); }
        if (d.w == 0) { int p = atomicAdd(&ctrl[0], 1); if (p < ECAP) astore_i(&e0src[p], src[4*q+3]); }
    }
    __threadfence();
    __shared__ int last;
    if (threadIdx.x == 0) last = (atomicAdd(&ctrl[15], 1) == gridDim.x - 1) ? 1 : 0;
    __syncthreads();
    if (last) {
        __threadfence();
        int cnt0 = aload_i(&ctrl[0]); if (cnt0 > ECAP) cnt0 = ECAP;
        for (int j = threadIdx.x; j <= cnt0; j += blockDim.x) {
            int n = (j < cnt0) ? aload_i(&e0src[j]) : 0;   // entry cnt0 = node 0 (self-loop)
            int old = atomicCAS(&flag[n], -1, j);
            if (old == -1) S_node[j] = n;                  // winner owns identifier j
        }
    }
}

// ---------------- K2: scan dst for dst in S -> flat elist + per-k bins + degS; last block builds T + dinvS ----------------
__global__ void k2_pass2(const int4* __restrict__ dst4, const int* __restrict__ src,
                         const int* __restrict__ flag, int* __restrict__ ctrl,
                         int* __restrict__ elist_src, int* __restrict__ elist_m,
                         int* __restrict__ ebin, int* __restrict__ degS,
                         int* __restrict__ flag2, float* __restrict__ dinvS) {
    int i = blockIdx.x * blockDim.x + threadIdx.x;
    int stride = gridDim.x * blockDim.x;
    const int n4 = N_EDGES / 4;
    for (int q = i; q < n4; q += stride) {
        int4 d = dst4[q];
        int dd[4] = {d.x, d.y, d.z, d.w};
        #pragma unroll
        for (int j = 0; j < 4; j++) {
            int k = flag[dd[j]];
            if (k >= 0) {
                int u = src[4*q+j];
                int p = atomicAdd(&ctrl[1], 1);
                int slot = atomicAdd(&degS[k], 1);      // true in-degree of S-node k
                if (p < ELCAP) {
                    astore_i(&elist_src[p], u);
                    if (slot < BINCAP) ebin[k * BINCAP + slot] = p;
                }
            }
        }
    }
    __threadfence();
    __shared__ int last;
    if (threadIdx.x == 0) last = (atomicAdd(&ctrl[14], 1) == gridDim.x - 1) ? 1 : 0;
    __syncthreads();
    if (last) {
        __threadfence();
        int cnt = aload_i(&ctrl[1]); if (cnt > ELCAP) cnt = ELCAP;
        for (int p = threadIdx.x; p < cnt; p += blockDim.x) {
            int u = aload_i(&elist_src[p]);
            int old = atomicCAS(&flag2[u], -1, p);      // T-id = winning flat entry index
            elist_m[p] = (old == -1) ? p : old;
        }
        for (int k = threadIdx.x; k < SCAP; k += blockDim.x)
            dinvS[k] = rsqrtf((float)(aload_i(&degS[k]) + 1));
    }
}

// ---------------- K3: scan dst -> in-degree of T nodes ----------------
__global__ void k3_pass3(const int4* __restrict__ dst4, const int* __restrict__ flag2,
                         int* __restrict__ degT) {
    int i = blockIdx.x * blockDim.x + threadIdx.x;
    int stride = gridDim.x * blockDim.x;
    const int n4 = N_EDGES / 4;
    for (int q = i; q < n4; q += stride) {
        int4 d = dst4[q];
        int m;
        m = flag2[d.x]; if (m >= 0) atomicAdd(&degT[m], 1);
        m = flag2[d.y]; if (m >= 0) atomicAdd(&degT[m], 1);
        m = flag2[d.z]; if (m >= 0) atomicAdd(&degT[m], 1);
        m = flag2[d.w]; if (m >= 0) atomicAdd(&degT[m], 1);
    }
}

// ---------------- K4: layer1 per S-node (bin gather + GEMV + relu); last block runs layer2 ----------------
__global__ void k4_layers(const int* __restrict__ ctrl, const int* __restrict__ S_node,
                          const float* __restrict__ dinvS, const int* __restrict__ degS,
                          const int* __restrict__ degT, const int* __restrict__ ebin,
                          const int* __restrict__ elist_src, const int* __restrict__ elist_m,
                          const int* __restrict__ e0src, const int* __restrict__ flag,
                          const float* __restrict__ x, const float* __restrict__ W1,
                          const float* __restrict__ b1, const float* __restrict__ W2,
                          const float* __restrict__ b2, float* __restrict__ h1,
                          float* __restrict__ out) {
    int k = blockIdx.x;
    int t = threadIdx.x;                  // 128 threads
    int n = S_node[k];
    if (n >= 0) {                          // block-uniform branch
        __shared__ int   su[BINCAP];
        __shared__ float snorm[BINCAP];
        __shared__ float vsm[IN_DIM];
        int slots = degS[k]; if (slots > BINCAP) slots = BINCAP;
        float dk = dinvS[k];
        if (t < slots) {
            int p = ebin[k * BINCAP + t];
            su[t] = elist_src[p];
            snorm[t] = rsqrtf((float)(degT[elist_m[p]] + 1)) * dk;
        }
        __syncthreads();
        float v = x[(size_t)n * IN_DIM + t] * dk * dk;   // self-loop
        for (int s = 0; s < slots; s++)
            v += x[(size_t)su[s] * IN_DIM + t] * snorm[s];
        vsm[t] = v;
        __syncthreads();
        float h = b1[t];
        #pragma unroll 8
        for (int j = 0; j < IN_DIM; j++) h += vsm[j] * W1[j * HID_DIM + t];
        astore_f(&h1[k * HID_DIM + t], fmaxf(h, 0.f));
    }
    // arrival (all blocks, including unclaimed ids)
    __threadfence();
    __shared__ int lastb;
    if (t == 0) lastb = (atomicAdd((int*)&ctrl[13], 1) == gridDim.x - 1) ? 1 : 0;
    __syncthreads();
    if (lastb) {
        __threadfence();
        __shared__ float msm[HID_DIM];
        int cnt0 = aload_i(&ctrl[0]); if (cnt0 > ECAP) cnt0 = ECAP;
        int k0 = flag[0];
        float dinv0 = dinvS[k0];
        float s = aload_f(&h1[k0 * HID_DIM + t]) * dinv0 * dinv0;   // self-loop
        #pragma unroll 4
        for (int i = 0; i < cnt0; i++) {
            int kk = flag[e0src[i]];
            s += aload_f(&h1[kk * HID_DIM + t]) * dinvS[kk] * dinv0;
        }
        msm[t] = s;
        __syncthreads();
        for (int o = t; o < OUT_DIM; o += blockDim.x) {
            float sum = b2[o];
            #pragma unroll 8
            for (int j = 0; j < HID_DIM; j++) sum += msm[j] * W2[j * OUT_DIM + o];
            out[o] = sum;
        }
    }
}

static inline char* align16(char* p) { return (char*)(((uintptr_t)p + 15) & ~(uintptr_t)15); }

extern "C" void kernel_launch(void* const* d_in, const int* in_sizes, int n_in,
                              void* d_out, int out_size, void* d_ws, size_t ws_size,
                              hipStream_t stream) {
    const float* x  = (const float*)d_in[0];
    const int*   ei = (const int*)d_in[1];           // edge_index flattened [2, E]
    const float* W1 = (const float*)d_in[2];
    const float* b1 = (const float*)d_in[3];
    const float* W2 = (const float*)d_in[4];
    const float* b2 = (const float*)d_in[5];
    float* out = (float*)d_out;

    const int*  src  = ei;                           // edge_index[0]
    const int4* dst4 = (const int4*)(ei + N_EDGES);  // edge_index[1], 16B-aligned

    // workspace carve-up (~1.1 MB), all 16B-aligned
    char* w = (char*)d_ws;
    int*   flag      = (int*)w;   w = align16(w + sizeof(int) * N_NODES);
    int*   flag2     = (int*)w;   w = align16(w + sizeof(int) * N_NODES);
    int*   ctrl      = (int*)w;   w = align16(w + sizeof(int) * 16);
    int*   e0src     = (int*)w;   w = align16(w + sizeof(int) * ECAP);
    int*   S_node    = (int*)w;   w = align16(w + sizeof(int) * SCAP);
    int*   degS      = (int*)w;   w = align16(w + sizeof(int) * SCAP);
    float* dinvS     = (float*)w; w = align16(w + sizeof(float) * SCAP);
    int*   elist_src = (int*)w;   w = align16(w + sizeof(int) * ELCAP);
    int*   elist_m   = (int*)w;   w = align16(w + sizeof(int) * ELCAP);
    int*   degT      = (int*)w;   w = align16(w + sizeof(int) * ELCAP);
    int*   ebin      = (int*)w;   w = align16(w + sizeof(int) * SCAP * BINCAP);
    float* h1        = (float*)w; w = align16(w + sizeof(float) * SCAP * HID_DIM);

    k0_init <<<256, 256, 0, stream>>>(flag, flag2, S_node, degS, degT, ctrl);
    k1_pass1<<<1024, 256, 0, stream>>>(dst4, src, ctrl, e0src, flag, S_node);
    k2_pass2<<<1024, 256, 0, stream>>>(dst4, src, flag, ctrl, elist_src, elist_m,
                                       ebin, degS, flag2, dinvS);
    k3_pass3<<<1024, 256, 0, stream>>>(dst4, flag2, degT);
    k4_layers<<<SCAP, IN_DIM, 0, stream>>>(ctrl, S_node, dinvS, degS, degT, ebin,
                                           elist_src, elist_m, e0src, flag,
                                           x, W1, b1, W2, b2, h1, out);
}

// Round 6
// 44.675 us; speedup vs baseline: 3.8410x; 3.8410x over previous
//
#include <hip/hip_runtime.h>

#define N_NODES 100000
#define N_EDGES 1600000
#define IN_DIM  128
#define HID_DIM 128
#define OUT_DIM 256

#define ECAP   192   // cap on edges into node 0 (expected ~16; huge margin)
#define SCAP   193   // S identifiers: ECAP+1
#define ELCAP  4096  // cap on edges into S (expected ~290)
#define BINCAP 128   // per-S-node edge bin (expected ~16)

#define NQ (N_EDGES/4)                  // 400000 int4 groups of dst
#define SCAN_BLOCKS ((NQ + 255) / 256)  // 1563

// ctrl: [0]=edges into node 0, [1]=elist count, [2]=k0 id (dedup id of node 0)

// ---------------- kA: clear control words (must precede kB's atomics) ----------------
__global__ void kA_ctrl(int* __restrict__ ctrl) {
    if (threadIdx.x < 16) ctrl[threadIdx.x] = 0;
}

// ---------------- kB: scan dst==0 -> e0src; bulk clears for later kernels ----------------
__global__ void kB_scan0(const int4* __restrict__ dst4, const int* __restrict__ src,
                         int* __restrict__ ctrl, int* __restrict__ e0src,
                         int* __restrict__ flag2, int* __restrict__ ebin,
                         int* __restrict__ degS, int* __restrict__ degT,
                         int* __restrict__ S_node) {
    int gid = blockIdx.x * blockDim.x + threadIdx.x;
    // clears (data consumed only after this kernel's boundary; disjoint from scan writes)
    if (gid < N_NODES/4) ((int4*)flag2)[gid] = make_int4(-1, -1, -1, -1);
    if (gid < SCAP*BINCAP/4) ((int4*)ebin)[gid] = make_int4(0, 0, 0, 0);
    if (gid < SCAP) { degS[gid] = 0; S_node[gid] = -1; }
    if (gid < ELCAP) degT[gid] = 0;
    // scan: exactly one int4 of dst per thread
    if (gid < NQ) {
        int4 d = dst4[gid];
        if (d.x == 0) { int p = atomicAdd(&ctrl[0], 1); if (p < ECAP) e0src[p] = src[4*gid+0]; }
        if (d.y == 0) { int p = atomicAdd(&ctrl[0], 1); if (p < ECAP) e0src[p] = src[4*gid+1]; }
        if (d.z == 0) { int p = atomicAdd(&ctrl[0], 1); if (p < ECAP) e0src[p] = src[4*gid+2]; }
        if (d.w == 0) { int p = atomicAdd(&ctrl[0], 1); if (p < ECAP) e0src[p] = src[4*gid+3]; }
    }
}

// ---------------- kC: per-block LDS dedup of S; scan dst in S -> elist + bins + degS ----------------
__global__ void kC_pass2(const int4* __restrict__ dst4, const int* __restrict__ src,
                         int* __restrict__ ctrl, const int* __restrict__ e0src,
                         int* __restrict__ S_node, int* __restrict__ e0k,
                         int* __restrict__ elist_src, int* __restrict__ ebin,
                         int* __restrict__ degS) {
    __shared__ int nodes[SCAP];
    __shared__ int firstid[SCAP];
    __shared__ int scn[SCAP];   // compact S node list
    __shared__ int sci[SCAP];   // compact S id list
    __shared__ int m;
    int t = threadIdx.x;
    int cnt0 = ctrl[0]; if (cnt0 > ECAP) cnt0 = ECAP;
    if (t == 0) m = 0;
    for (int i = t; i <= cnt0; i += blockDim.x)
        nodes[i] = (i < cnt0) ? e0src[i] : 0;     // entry cnt0 = node 0 (layer-2 self-loop)
    __syncthreads();
    for (int i = t; i <= cnt0; i += blockDim.x) {
        int n = nodes[i]; int id = i;
        for (int j = 0; j < i; j++) if (nodes[j] == n) { id = j; break; }
        firstid[i] = id;
        if (id == i) { int pos = atomicAdd(&m, 1); scn[pos] = n; sci[pos] = i; }
    }
    __syncthreads();
    int snum = m;
    if (blockIdx.x == 0) {                        // publish canonical maps for later kernels
        for (int i = t; i <= cnt0; i += blockDim.x) {
            e0k[i] = firstid[i];
            if (firstid[i] == i) S_node[i] = nodes[i];
        }
        if (t == 0) ctrl[2] = firstid[cnt0];      // id of node 0
    }
    // scan: one int4 of dst per thread; membership via ~17 LDS compares (no L2 lookups)
    int q = blockIdx.x * blockDim.x + t;
    if (q < NQ) {
        int4 d = dst4[q];
        int ka = -1, kb = -1, kc = -1, kd = -1;
        for (int s = 0; s < snum; s++) {
            int nn = scn[s], ii = sci[s];
            if (d.x == nn) ka = ii;
            if (d.y == nn) kb = ii;
            if (d.z == nn) kc = ii;
            if (d.w == nn) kd = ii;
        }
        int ks[4] = {ka, kb, kc, kd};
        #pragma unroll
        for (int j = 0; j < 4; j++) {
            int k = ks[j];
            if (k >= 0) {
                int slot = atomicAdd(&degS[k], 1);          // true in-degree count
                if (slot < BINCAP) {
                    int p = atomicAdd(&ctrl[1], 1);
                    if (p < ELCAP) { elist_src[p] = src[4*q + j]; ebin[k*BINCAP + slot] = p; }
                }
            }
        }
    }
}

// ---------------- kD: dedup T via CAS-claim; elist_m; dinvS ----------------
__global__ void kD_buildT(const int* __restrict__ ctrl, const int* __restrict__ elist_src,
                          int* __restrict__ flag2, int* __restrict__ elist_m,
                          const int* __restrict__ degS, float* __restrict__ dinvS) {
    int cnt = ctrl[1]; if (cnt > ELCAP) cnt = ELCAP;
    int t = threadIdx.x;
    for (int p = t; p < cnt; p += blockDim.x) {
        int u = elist_src[p];
        int old = atomicCAS(&flag2[u], -1, p);   // T-id = winning elist entry index
        elist_m[p] = (old == -1) ? p : old;
    }
    for (int k = t; k < SCAP; k += blockDim.x)
        dinvS[k] = rsqrtf((float)(degS[k] + 1)); // +1: self-loop
}

// ---------------- kE: scan dst -> in-degree of T nodes ----------------
__global__ void kE_pass3(const int4* __restrict__ dst4, const int* __restrict__ flag2,
                         int* __restrict__ degT) {
    int gid = blockIdx.x * blockDim.x + threadIdx.x;
    if (gid >= NQ) return;
    int4 d = dst4[gid];
    int m;
    m = flag2[d.x]; if (m >= 0) atomicAdd(&degT[m], 1);
    m = flag2[d.y]; if (m >= 0) atomicAdd(&degT[m], 1);
    m = flag2[d.z]; if (m >= 0) atomicAdd(&degT[m], 1);
    m = flag2[d.w]; if (m >= 0) atomicAdd(&degT[m], 1);
}

// ---------------- kF: layer 1 per S-node: bin gather + GEMV + bias + relu ----------------
__global__ void kF_layer1(const int* __restrict__ S_node, const float* __restrict__ dinvS,
                          const int* __restrict__ degS, const int* __restrict__ degT,
                          const int* __restrict__ ebin, const int* __restrict__ elist_src,
                          const int* __restrict__ elist_m, const float* __restrict__ x,
                          const float* __restrict__ W1, const float* __restrict__ b1,
                          float* __restrict__ h1) {
    int k = blockIdx.x;
    int n = S_node[k];
    if (n < 0) return;                 // unclaimed identifier
    int t = threadIdx.x;               // 128 threads
    __shared__ int   su[BINCAP];
    __shared__ float snorm[BINCAP];
    __shared__ float vsm[IN_DIM];
    int slots = degS[k]; if (slots > BINCAP) slots = BINCAP;
    float dk = dinvS[k];
    if (t < slots) {
        int p = ebin[k*BINCAP + t];
        su[t] = elist_src[p];
        snorm[t] = rsqrtf((float)(degT[elist_m[p]] + 1)) * dk;
    }
    __syncthreads();
    float v = x[(size_t)n * IN_DIM + t] * dk * dk;      // self-loop
    for (int s = 0; s < slots; s++)
        v += x[(size_t)su[s] * IN_DIM + t] * snorm[s];
    vsm[t] = v;
    __syncthreads();
    float h = b1[t];
    #pragma unroll 8
    for (int j = 0; j < IN_DIM; j++) h += vsm[j] * W1[j * HID_DIM + t];
    h1[k * HID_DIM + t] = fmaxf(h, 0.f);
}

// ---------------- kG: layer 2 for node 0 only ----------------
__global__ void kG_layer2(const int* __restrict__ ctrl, const int* __restrict__ e0k,
                          const float* __restrict__ dinvS, const float* __restrict__ h1,
                          const float* __restrict__ W2, const float* __restrict__ b2,
                          float* __restrict__ out) {
    __shared__ float msm[HID_DIM];
    int t = threadIdx.x;               // 256 threads
    int cnt0 = ctrl[0]; if (cnt0 > ECAP) cnt0 = ECAP;
    int k0 = ctrl[2];
    if (t < HID_DIM) {
        float dinv0 = dinvS[k0];
        float s = h1[k0 * HID_DIM + t] * dinv0 * dinv0;  // self-loop
        for (int i = 0; i < cnt0; i++) {
            int kk = e0k[i];
            s += h1[kk * HID_DIM + t] * dinvS[kk] * dinv0;
        }
        msm[t] = s;
    }
    __syncthreads();
    float sum = b2[t];
    #pragma unroll 8
    for (int j = 0; j < HID_DIM; j++) sum += msm[j] * W2[j * OUT_DIM + t];
    out[t] = sum;
}

static inline char* align16(char* p) { return (char*)(((uintptr_t)p + 15) & ~(uintptr_t)15); }

extern "C" void kernel_launch(void* const* d_in, const int* in_sizes, int n_in,
                              void* d_out, int out_size, void* d_ws, size_t ws_size,
                              hipStream_t stream) {
    const float* x  = (const float*)d_in[0];
    const int*   ei = (const int*)d_in[1];           // edge_index flattened [2, E] (int32)
    const float* W1 = (const float*)d_in[2];
    const float* b1 = (const float*)d_in[3];
    const float* W2 = (const float*)d_in[4];
    const float* b2 = (const float*)d_in[5];
    float* out = (float*)d_out;

    const int*  src  = ei;                           // edge_index[0]
    const int4* dst4 = (const int4*)(ei + N_EDGES);  // edge_index[1], 16B-aligned

    // workspace carve-up (~650 KB), 16B-aligned
    char* w = (char*)d_ws;
    int*   flag2     = (int*)w;   w = align16(w + sizeof(int) * N_NODES);
    int*   ctrl      = (int*)w;   w = align16(w + sizeof(int) * 16);
    int*   e0src     = (int*)w;   w = align16(w + sizeof(int) * ECAP);
    int*   e0k       = (int*)w;   w = align16(w + sizeof(int) * SCAP);
    int*   S_node    = (int*)w;   w = align16(w + sizeof(int) * SCAP);
    int*   degS      = (int*)w;   w = align16(w + sizeof(int) * SCAP);
    float* dinvS     = (float*)w; w = align16(w + sizeof(float) * SCAP);
    int*   elist_src = (int*)w;   w = align16(w + sizeof(int) * ELCAP);
    int*   elist_m   = (int*)w;   w = align16(w + sizeof(int) * ELCAP);
    int*   degT      = (int*)w;   w = align16(w + sizeof(int) * ELCAP);
    int*   ebin      = (int*)w;   w = align16(w + sizeof(int) * SCAP * BINCAP);
    float* h1        = (float*)w; w = align16(w + sizeof(float) * SCAP * HID_DIM);

    kA_ctrl  <<<1, 64, 0, stream>>>(ctrl);
    kB_scan0 <<<SCAN_BLOCKS, 256, 0, stream>>>(dst4, src, ctrl, e0src,
                                               flag2, ebin, degS, degT, S_node);
    kC_pass2 <<<SCAN_BLOCKS, 256, 0, stream>>>(dst4, src, ctrl, e0src, S_node, e0k,
                                               elist_src, ebin, degS);
    kD_buildT<<<1, 512, 0, stream>>>(ctrl, elist_src, flag2, elist_m, degS, dinvS);
    kE_pass3 <<<SCAN_BLOCKS, 256, 0, stream>>>(dst4, flag2, degT);
    kF_layer1<<<SCAP, IN_DIM, 0, stream>>>(S_node, dinvS, degS, degT, ebin,
                                           elist_src, elist_m, x, W1, b1, h1);
    kG_layer2<<<1, OUT_DIM, 0, stream>>>(ctrl, e0k, dinvS, h1, W2, b2, out);
}

// Round 7
// 40.938 us; speedup vs baseline: 4.1916x; 1.0913x over previous
//
#include <hip/hip_runtime.h>

#define N_NODES 100000
#define N_EDGES 1600000
#define IN_DIM  128
#define HID_DIM 128
#define OUT_DIM 256

#define ECAP   192   // cap on edges into node 0 (expected ~16; huge margin)
#define SCAP   193   // S identifiers: ECAP+1
#define ELCAP  4096  // cap on edges into S (expected ~290)
#define BINCAP 128   // per-S-node edge bin (expected ~16)

#define NQ (N_EDGES/4)                  // 400000 int4 groups of dst
#define SCAN_BLOCKS ((NQ + 255) / 256)  // 1563

// ctrl: [0]=edges into node 0 (raw count), [1]=elist cursor, [2]=k0 id (dedup id of node 0)

// ---------------- kA: clear control words (must precede kB's atomics) ----------------
__global__ void kA_ctrl(int* __restrict__ ctrl) {
    if (threadIdx.x < 16) ctrl[threadIdx.x] = 0;
}

// ---------------- kB: scan dst==0 -> e0src; bulk clears; out = b2 ----------------
__global__ void kB_scan0(const int4* __restrict__ dst4, const int* __restrict__ src,
                         int* __restrict__ ctrl, int* __restrict__ e0src,
                         int* __restrict__ flag2, int* __restrict__ degS,
                         int* __restrict__ degT, int* __restrict__ S_node,
                         const float* __restrict__ b2, float* __restrict__ out) {
    int gid = blockIdx.x * blockDim.x + threadIdx.x;
    // clears (consumed only after this kernel's boundary)
    if (gid < N_NODES/4) ((int4*)flag2)[gid] = make_int4(-1, -1, -1, -1);
    if (gid < SCAP) { degS[gid] = 0; S_node[gid] = -1; }
    if (gid < ELCAP) degT[gid] = 0;
    if (gid < OUT_DIM) out[gid] = b2[gid];      // kF accumulates on top
    // scan: exactly one int4 of dst per thread
    if (gid < NQ) {
        int4 d = dst4[gid];
        if (d.x == 0) { int p = atomicAdd(&ctrl[0], 1); if (p < ECAP) e0src[p] = src[4*gid+0]; }
        if (d.y == 0) { int p = atomicAdd(&ctrl[0], 1); if (p < ECAP) e0src[p] = src[4*gid+1]; }
        if (d.z == 0) { int p = atomicAdd(&ctrl[0], 1); if (p < ECAP) e0src[p] = src[4*gid+2]; }
        if (d.w == 0) { int p = atomicAdd(&ctrl[0], 1); if (p < ECAP) e0src[p] = src[4*gid+3]; }
    }
}

// ---------------- kC: per-block LDS dedup of S; scan dst in S -> elist + bins + degS;
//                      inline order-independent CAS-claim of T ids ----------------
__global__ void kC_pass2(const int4* __restrict__ dst4, const int* __restrict__ src,
                         int* __restrict__ ctrl, const int* __restrict__ e0src,
                         int* __restrict__ S_node, int* __restrict__ e0k,
                         int* __restrict__ elist_src, int* __restrict__ elist_m,
                         int* __restrict__ ebin, int* __restrict__ degS,
                         int* __restrict__ flag2) {
    __shared__ int nodes[SCAP];
    __shared__ int firstid[SCAP];
    __shared__ int scn[SCAP];   // compact S node list
    __shared__ int sci[SCAP];   // compact S id list
    __shared__ int m;
    int t = threadIdx.x;
    int cnt0 = ctrl[0]; if (cnt0 > ECAP) cnt0 = ECAP;
    if (t == 0) m = 0;
    for (int i = t; i <= cnt0; i += blockDim.x)
        nodes[i] = (i < cnt0) ? e0src[i] : 0;     // entry cnt0 = node 0 (layer-2 self-loop)
    __syncthreads();
    for (int i = t; i <= cnt0; i += blockDim.x) {
        int n = nodes[i]; int id = i;
        for (int j = 0; j < i; j++) if (nodes[j] == n) { id = j; break; }
        firstid[i] = id;
        if (id == i) { int pos = atomicAdd(&m, 1); scn[pos] = n; sci[pos] = i; }
    }
    __syncthreads();
    int snum = m;
    if (blockIdx.x == 0) {                        // publish canonical maps for kF
        for (int i = t; i <= cnt0; i += blockDim.x) {
            e0k[i] = firstid[i];
            if (firstid[i] == i) S_node[i] = nodes[i];
        }
        if (t == 0) ctrl[2] = firstid[cnt0];      // id of node 0
    }
    // scan: one int4 of dst per thread; membership via ~17 LDS compares
    int q = blockIdx.x * blockDim.x + t;
    if (q < NQ) {
        int4 d = dst4[q];
        int ka = -1, kb = -1, kc = -1, kd = -1;
        for (int s = 0; s < snum; s++) {
            int nn = scn[s], ii = sci[s];
            if (d.x == nn) ka = ii;
            if (d.y == nn) kb = ii;
            if (d.z == nn) kc = ii;
            if (d.w == nn) kd = ii;
        }
        int ks[4] = {ka, kb, kc, kd};
        #pragma unroll
        for (int j = 0; j < 4; j++) {
            int k = ks[j];
            if (k >= 0) {
                int u = src[4*q + j];
                int slot = atomicAdd(&degS[k], 1);        // true in-degree of S-node k
                if (slot < BINCAP) {
                    int p = atomicAdd(&ctrl[1], 1);
                    if (p < ELCAP) {
                        elist_src[p] = u;
                        int old = atomicCAS(&flag2[u], -1, p);   // T-id claim, order-free
                        elist_m[p] = (old == -1) ? p : old;
                        ebin[k*BINCAP + slot] = p;
                    }
                }
            }
        }
    }
}

// ---------------- kE: scan dst -> in-degree of T nodes ----------------
__global__ void kE_pass3(const int4* __restrict__ dst4, const int* __restrict__ flag2,
                         int* __restrict__ degT) {
    int gid = blockIdx.x * blockDim.x + threadIdx.x;
    if (gid >= NQ) return;
    int4 d = dst4[gid];
    int m;
    m = flag2[d.x]; if (m >= 0) atomicAdd(&degT[m], 1);
    m = flag2[d.y]; if (m >= 0) atomicAdd(&degT[m], 1);
    m = flag2[d.z]; if (m >= 0) atomicAdd(&degT[m], 1);
    m = flag2[d.w]; if (m >= 0) atomicAdd(&degT[m], 1);
}

// ---------------- kF: layer 1 per S-node + layer-2 contribution via linearity ----------------
__global__ void kF_layers(const int* __restrict__ ctrl, const int* __restrict__ S_node,
                          const int* __restrict__ degS, const int* __restrict__ degT,
                          const int* __restrict__ ebin, const int* __restrict__ elist_src,
                          const int* __restrict__ elist_m, const int* __restrict__ e0k,
                          const float* __restrict__ x, const float* __restrict__ W1,
                          const float* __restrict__ b1, const float* __restrict__ W2,
                          float* __restrict__ out) {
    int k = blockIdx.x;
    int n = S_node[k];
    if (n < 0) return;                 // unclaimed identifier
    int t = threadIdx.x;               // 128 threads
    __shared__ int   su[BINCAP];
    __shared__ float snorm[BINCAP];
    __shared__ float vsm[IN_DIM];
    __shared__ float hsm[HID_DIM];
    __shared__ int   csum;
    int dgk = degS[k];
    int slots = dgk; if (slots > BINCAP) slots = BINCAP;
    float dk = rsqrtf((float)(dgk + 1));
    if (t < slots) {
        int p = ebin[k*BINCAP + t];
        su[t] = elist_src[p];
        snorm[t] = rsqrtf((float)(degT[elist_m[p]] + 1)) * dk;
    }
    __syncthreads();
    float v = x[(size_t)n * IN_DIM + t] * dk * dk;      // self-loop
    for (int s = 0; s < slots; s++)
        v += x[(size_t)su[s] * IN_DIM + t] * snorm[s];
    vsm[t] = v;
    __syncthreads();
    float h = b1[t];
    #pragma unroll 8
    for (int j = 0; j < IN_DIM; j++) h += vsm[j] * W1[j * HID_DIM + t];
    hsm[t] = fmaxf(h, 0.f);
    if (t == 0) csum = 0;
    __syncthreads();
    // layer-2 coefficient: c_k = multiplicity of k among edges into node 0
    int rawc = ctrl[0];
    int cnt0 = rawc; if (cnt0 > ECAP) cnt0 = ECAP;
    int c = 0;
    for (int i = t; i < cnt0; i += blockDim.x) if (e0k[i] == k) c++;
    if (c) atomicAdd(&csum, c);
    __syncthreads();
    float dinv0 = rsqrtf((float)(rawc + 1));
    float coef = dinv0 * ((float)csum * dk + ((k == ctrl[2]) ? dinv0 : 0.f));
    // out[o] += coef * (hsm @ W2[:,o]); 128 threads x 2 outputs
    #pragma unroll
    for (int r = 0; r < 2; r++) {
        int o = t + r * 128;
        float sum = 0.f;
        #pragma unroll 8
        for (int j = 0; j < HID_DIM; j++) sum += hsm[j] * W2[j * OUT_DIM + o];
        atomicAdd(&out[o], coef * sum);
    }
}

static inline char* align16(char* p) { return (char*)(((uintptr_t)p + 15) & ~(uintptr_t)15); }

extern "C" void kernel_launch(void* const* d_in, const int* in_sizes, int n_in,
                              void* d_out, int out_size, void* d_ws, size_t ws_size,
                              hipStream_t stream) {
    const float* x  = (const float*)d_in[0];
    const int*   ei = (const int*)d_in[1];           // edge_index flattened [2, E] (int32)
    const float* W1 = (const float*)d_in[2];
    const float* b1 = (const float*)d_in[3];
    const float* W2 = (const float*)d_in[4];
    const float* b2 = (const float*)d_in[5];
    float* out = (float*)d_out;

    const int*  src  = ei;                           // edge_index[0]
    const int4* dst4 = (const int4*)(ei + N_EDGES);  // edge_index[1], 16B-aligned

    // workspace carve-up (~550 KB), 16B-aligned
    char* w = (char*)d_ws;
    int* flag2     = (int*)w;  w = align16(w + sizeof(int) * N_NODES);
    int* ctrl      = (int*)w;  w = align16(w + sizeof(int) * 16);
    int* e0src     = (int*)w;  w = align16(w + sizeof(int) * ECAP);
    int* e0k       = (int*)w;  w = align16(w + sizeof(int) * SCAP);
    int* S_node    = (int*)w;  w = align16(w + sizeof(int) * SCAP);
    int* degS      = (int*)w;  w = align16(w + sizeof(int) * SCAP);
    int* elist_src = (int*)w;  w = align16(w + sizeof(int) * ELCAP);
    int* elist_m   = (int*)w;  w = align16(w + sizeof(int) * ELCAP);
    int* degT      = (int*)w;  w = align16(w + sizeof(int) * ELCAP);
    int* ebin      = (int*)w;  w = align16(w + sizeof(int) * SCAP * BINCAP);

    kA_ctrl <<<1, 64, 0, stream>>>(ctrl);
    kB_scan0<<<SCAN_BLOCKS, 256, 0, stream>>>(dst4, src, ctrl, e0src,
                                              flag2, degS, degT, S_node, b2, out);
    kC_pass2<<<SCAN_BLOCKS, 256, 0, stream>>>(dst4, src, ctrl, e0src, S_node, e0k,
                                              elist_src, elist_m, ebin, degS, flag2);
    kE_pass3<<<SCAN_BLOCKS, 256, 0, stream>>>(dst4, flag2, degT);
    kF_layers<<<SCAP, IN_DIM, 0, stream>>>(ctrl, S_node, degS, degT, ebin,
                                           elist_src, elist_m, e0k, x, W1, b1, W2, out);
}